// Round 11
// baseline (1927.051 us; speedup 1.0000x reference)
//
#include <hip/hip_runtime.h>
#include <hip/hip_bf16.h>

// STDP IF-neuron network, T=50 sequential steps. Pair-split persistent v8.
// x_seq [50,256,1024] f32, weight [2048,1024] f32 -> spike_trace [256,2048] f32.
//
// 256 blocks x 512 thr: block (slab = bid&127, half = bid>>7) owns h-slab
// slab*16..+16 jointly with its partner (slab, 1-half):
//   fwd/IF: block computes mem over the FULL d (chain order = rounds 4-10,
//           bit-identical) for its b-half (128 rows). Needs full W: both
//           blocks keep full W bf16 hi/lo frags in LDS.
//   wupd:   block computes dw over the full batch for its d-half, updates
//           its wreg (fp32 master, registers) + LDS frags, and ships the
//           refreshed bf16 W-half frags to its partner via global.
// Per-step pair exchange: s-frags 4KB + W-half frags 32KB, two flag
// handshakes (__hip_atomic AGENT; flags memset each launch -> replay-safe;
// 256 blocks <= 256 CUs and 2/CU also fits -> spins can't starve).
//
// LDS layout = FRAGMENT ORDER (same as packed global streams): every LDS
// read/write is lane-linear 16B/8B -> zero bank conflicts (round-10 counter
// showed 42.7M conflicts from the old XOR layout: 8-way on B-frag reads).

#define T_STEPS 50
#define BATCH   256
#define DIM     1024
#define HID     2048
#define HT      16
#define LR_OVER_B (0.005f / 256.0f)

// LDS: whF 32KB | wlF 32KB | slF 8KB  (frag order, chunk-major)
#define SMEM_BYTES (32768 + 32768 + 8192)

typedef __attribute__((ext_vector_type(8))) short short8v;
typedef __attribute__((ext_vector_type(4))) float f32x4;

static __device__ __forceinline__ ushort f32_to_bf16u(float f) {
    __hip_bfloat16 h = __float2bfloat16(f);
    return __builtin_bit_cast(unsigned short, h);
}
static __device__ __forceinline__ float bf16u_to_f32(ushort u) {
    __hip_bfloat16 h = __builtin_bit_cast(__hip_bfloat16, u);
    return __bfloat162float(h);
}

#define MFMA_B16 __builtin_amdgcn_mfma_f32_16x16x32_bf16

// ---------------- prep A: fwd fragment packing (unchanged, r10) -----------
// XF[t][bt=0..15][c=0..31][h=0..1][lane=0..63][8] ushorts.
__global__ __launch_bounds__(256) void prep_fwd(
    const float* __restrict__ x, ushort* __restrict__ XF)
{
    __shared__ float xs[16 * 1024];
    const int t  = blockIdx.x >> 4;
    const int bt = blockIdx.x & 15;
    const float* xrow = x + ((size_t)t * BATCH + bt * 16) * DIM;
    for (int i = threadIdx.x; i < 16 * 1024 / 4; i += 256)
        ((float4*)xs)[i] = ((const float4*)xrow)[i];
    __syncthreads();

    ushort* outb = XF + ((size_t)t * 16 + bt) * (32 * 2 * 512);
    for (int item = threadIdx.x; item < 32 * 64; item += 256) {
        const int c = item >> 6;
        const int l = item & 63;
        const int row = l & 15;
        const int col = c * 32 + (l >> 4) * 8;
        short8v hv, lv;
#pragma unroll
        for (int j = 0; j < 8; ++j) {
            float v = xs[row * 1024 + col + j];
            ushort h = f32_to_bf16u(v);
            hv[j] = (short)h;
            lv[j] = (short)f32_to_bf16u(v - bf16u_to_f32(h));
        }
        *(short8v*)(outb + ((size_t)c * 2 + 0) * 512 + l * 8) = hv;
        *(short8v*)(outb + ((size_t)c * 2 + 1) * 512 + l * 8) = lv;
    }
}

// ---------------- prep B: wupd fragment packing (unchanged, r10) ----------
// XW[t][dt=0..63][c=0..7][h=0..1][lane=0..63][8] ushorts.
__global__ __launch_bounds__(256) void prep_wupd(
    const float* __restrict__ x, ushort* __restrict__ XW)
{
    __shared__ float xs[256 * 16];
    const int t  = blockIdx.x >> 6;
    const int dt = blockIdx.x & 63;
    {
        const int b = threadIdx.x;
        const float* src = x + ((size_t)t * BATCH + b) * DIM + dt * 16;
#pragma unroll
        for (int q = 0; q < 4; ++q)
            ((float4*)&xs[b * 16])[q] = ((const float4*)src)[q];
    }
    __syncthreads();

    ushort* outb = XW + ((size_t)t * 64 + dt) * (8 * 2 * 512);
    for (int item = threadIdx.x; item < 8 * 64; item += 256) {
        const int c = item >> 6;
        const int l = item & 63;
        const int drow = l & 15;
        const int bbase = c * 32 + (l >> 4) * 8;
        short8v hv, lv;
#pragma unroll
        for (int j = 0; j < 8; ++j) {
            float v = xs[(bbase + j) * 16 + drow];
            ushort h = f32_to_bf16u(v);
            hv[j] = (short)h;
            lv[j] = (short)f32_to_bf16u(v - bf16u_to_f32(h));
        }
        *(short8v*)(outb + ((size_t)c * 2 + 0) * 512 + l * 8) = hv;
        *(short8v*)(outb + ((size_t)c * 2 + 1) * 512 + l * 8) = lv;
    }
}

// ---------------- THE pair-split persistent kernel ------------------------
__global__ __launch_bounds__(512, 2) void stdp_pair(
    const ushort* __restrict__ XF, const ushort* __restrict__ XW,
    const float* __restrict__ weight, float* __restrict__ out,
    ushort* __restrict__ sex,   // [256][2048] us: per (slab,half) s-frags 4KB
    ushort* __restrict__ wex,   // [256][16384] us: per (slab,half) W-half 32KB
    unsigned* __restrict__ flagS, unsigned* __restrict__ flagW)  // [256] each
{
    extern __shared__ char smem[];
    ushort* whF = (ushort*)smem;             // 32 chunks x 512 us
    ushort* wlF = whF + 32 * 512;
    ushort* slF = wlF + 32 * 512;            // 8 chunks x 512 us

    const int bid  = blockIdx.x;
    const int slab = bid & 127;
    const int half = bid >> 7;
    const int tid  = threadIdx.x;
    const int lane = tid & 63;
    const int w    = tid >> 6;               // wave 0..7
    const int fr   = lane & 15;
    const int rq   = (lane >> 4) * 4;
    const int h0   = slab * HT;
    const int self    = slab * 2 + half;
    const int partner = slab * 2 + (1 - half);

    ushort* sex_s = sex + (size_t)self * 2048;
    const ushort* sex_p = sex + (size_t)partner * 2048;
    ushort* wex_s = wex + (size_t)self * 16384;
    const ushort* wex_p = wex + (size_t)partner * 16384;

    // ---- init: full-W frag LDS (wave w: chunks 4w..4w+3) ----
#pragma unroll
    for (int q = 0; q < 4; ++q) {
        const int c   = w * 4 + q;
        const int row = lane & 15;
        const int col = c * 32 + (lane >> 4) * 8;
        const float* src = &weight[(size_t)(h0 + row) * DIM + col];
        short8v hv, lv;
#pragma unroll
        for (int j = 0; j < 8; ++j) {
            float v = src[j];
            ushort h = f32_to_bf16u(v);
            hv[j] = (short)h;
            lv[j] = (short)f32_to_bf16u(v - bf16u_to_f32(h));
        }
        *(short8v*)&whF[c * 512 + lane * 8] = hv;
        *(short8v*)&wlF[c * 512 + lane * 8] = lv;
    }
    // ---- wreg fp32 master: own d-half; lane owns h=h0+fr, d=half*512+w*64+tile*16+rq ----
    f32x4 wreg[4];
#pragma unroll
    for (int tile = 0; tile < 4; ++tile) {
        const int d = half * 512 + w * 64 + tile * 16 + rq;
        float4 wv = *(const float4*)&weight[(size_t)(h0 + fr) * DIM + d];
        wreg[tile][0] = wv.x; wreg[tile][1] = wv.y;
        wreg[tile][2] = wv.z; wreg[tile][3] = wv.w;
    }
    __syncthreads();

    const f32x4 z4 = {0.f, 0.f, 0.f, 0.f};
    f32x4 vmem = z4;
    f32x4 trc  = z4;

    // s-frag write constants: b = half*128 + w*16 + rq + j
    const int s_cg  = half * 4 + (w >> 1);                 // global s chunk
    const int s_l   = fr | (((w & 1) * 2 + (rq >> 3)) << 4);
    const int s_off = s_l * 8 + (rq & 4);

    for (int t = 0; t < T_STEPS; ++t) {
        // ============ fwd: mem(b-half, all d), chain order = r4-r10 =======
        const ushort* fbase = XF + (size_t)t * (16 * 32 * 2 * 512)
                            + (size_t)(half * 8 + w) * (32 * 2 * 512)
                            + lane * 8;
        f32x4 acc = z4;
        short8v GA[4][2];
#pragma unroll 1
        for (int g = 0; g < 8; ++g) {
#pragma unroll
            for (int c2 = 0; c2 < 4; ++c2) {
                const int cc = g * 4 + c2;
                GA[c2][0] = *(const short8v*)(fbase + ((size_t)cc * 2 + 0) * 512);
                GA[c2][1] = *(const short8v*)(fbase + ((size_t)cc * 2 + 1) * 512);
            }
#pragma unroll
            for (int c2 = 0; c2 < 4; ++c2) {
                const int cc = g * 4 + c2;
                short8v bh = *(const short8v*)&whF[cc * 512 + lane * 8];
                short8v bl = *(const short8v*)&wlF[cc * 512 + lane * 8];
                acc = MFMA_B16(GA[c2][0], bh, acc, 0, 0, 0);
                acc = MFMA_B16(GA[c2][0], bl, acc, 0, 0, 0);
                acc = MFMA_B16(GA[c2][1], bh, acc, 0, 0, 0);
            }
        }

        // ---- IF update (own b-half) + s frag to LDS + global ----
        {
            ushort4 sq; ushort* sp = &sq.x;
#pragma unroll
            for (int j = 0; j < 4; ++j) {
                float nv = vmem[j] + acc[j];
                bool fire = (nv >= 1.0f);
                vmem[j] = fire ? 0.0f : nv;
                trc[j] += fire ? 1.0f : 0.0f;
                sp[j] = fire ? (ushort)0x3F80 : (ushort)0;
            }
            *(ushort4*)&slF[s_cg * 512 + s_off] = sq;
            if (t < T_STEPS - 1)
                *(ushort4*)&sex_s[(s_cg - half * 4) * 512 + s_off] = sq;
        }

        if (t >= T_STEPS - 1) break;   // last step: trace done, no wupd

        __syncthreads();               // slF own chunks + sex writes issued
        if (tid == 0) {
            __hip_atomic_store(&flagS[self], (unsigned)(t + 1),
                               __ATOMIC_RELEASE, __HIP_MEMORY_SCOPE_AGENT);
            while (__hip_atomic_load(&flagS[partner], __ATOMIC_ACQUIRE,
                                     __HIP_MEMORY_SCOPE_AGENT) < (unsigned)(t + 1))
                __builtin_amdgcn_s_sleep(1);
        }
        __syncthreads();
        // ---- import partner s chunks (waves 0..3) ----
        if (w < 4) {
            short8v sv = *(const short8v*)&sex_p[w * 512 + lane * 8];
            *(short8v*)&slF[((1 - half) * 4 + w) * 512 + lane * 8] = sv;
        }
        __syncthreads();               // slF complete (all 8 chunks)

        // ============ wupd: dw(d-half, full batch), W update ==============
        {
            const ushort* xwt = XW + (size_t)t * (64 * 8 * 2 * 512);
            short8v HA[4][2];
#pragma unroll
            for (int tile = 0; tile < 4; ++tile) {
                f32x4 du = z4;
                const int dt_g = half * 32 + w * 4 + tile;
                const ushort* tbase = xwt + (size_t)dt_g * (8 * 2 * 512) + lane * 8;
#pragma unroll 1
                for (int hg = 0; hg < 2; ++hg) {
#pragma unroll
                    for (int c2 = 0; c2 < 4; ++c2) {
                        const int cc = hg * 4 + c2;
                        HA[c2][0] = *(const short8v*)(tbase + ((size_t)cc * 2 + 0) * 512);
                        HA[c2][1] = *(const short8v*)(tbase + ((size_t)cc * 2 + 1) * 512);
                    }
#pragma unroll
                    for (int c2 = 0; c2 < 4; ++c2) {
                        const int cc = hg * 4 + c2;
                        short8v sf = *(const short8v*)&slF[cc * 512 + lane * 8];
                        du = MFMA_B16(HA[c2][0], sf, du, 0, 0, 0);
                        du = MFMA_B16(HA[c2][1], sf, du, 0, 0, 0);
                    }
                }
                // ---- W master update + re-split, frag-order stores ----
                ushort4 hi4, lo4;
                ushort* hp = &hi4.x; ushort* lp = &lo4.x;
#pragma unroll
                for (int j = 0; j < 4; ++j) {
                    float wv = fmaf(LR_OVER_B, du[j], wreg[tile][j]);
                    wreg[tile][j] = wv;
                    ushort hb = f32_to_bf16u(wv);
                    hp[j] = hb;
                    lp[j] = f32_to_bf16u(wv - bf16u_to_f32(hb));
                }
                const int c_l = w * 2 + (tile >> 1);           // 0..15 local chunk
                const int l_w = fr | ((((tile * 2) + (rq >> 3)) & 3) << 4);
                const int off = l_w * 8 + (rq & 4);
                *(ushort4*)&whF[(half * 16 + c_l) * 512 + off] = hi4;
                *(ushort4*)&wlF[(half * 16 + c_l) * 512 + off] = lo4;
                *(ushort4*)&wex_s[(c_l * 2 + 0) * 512 + off] = hi4;
                *(ushort4*)&wex_s[(c_l * 2 + 1) * 512 + off] = lo4;
            }
        }

        __syncthreads();               // wex writes issued by all waves
        if (tid == 0) {
            __hip_atomic_store(&flagW[self], (unsigned)(t + 1),
                               __ATOMIC_RELEASE, __HIP_MEMORY_SCOPE_AGENT);
            while (__hip_atomic_load(&flagW[partner], __ATOMIC_ACQUIRE,
                                     __HIP_MEMORY_SCOPE_AGENT) < (unsigned)(t + 1))
                __builtin_amdgcn_s_sleep(1);
        }
        __syncthreads();
        // ---- import partner W-half frags (all waves, 4 items each) ----
#pragma unroll
        for (int q = 0; q < 4; ++q) {
            const int item = w * 4 + q;          // = chunk*2 + plane
            short8v v = *(const short8v*)&wex_p[item * 512 + lane * 8];
            ushort* dst = (q & 1) ? wlF : whF;
            *(short8v*)&dst[((1 - half) * 16 + (item >> 1)) * 512 + lane * 8] = v;
        }
        __syncthreads();               // whF/wlF consistent for next fwd
    }

    // ---- write trace (own b-half) to d_out [B,H] ----
#pragma unroll
    for (int j = 0; j < 4; ++j) {
        const int b = half * 128 + w * 16 + rq + j;
        out[(size_t)b * HID + h0 + fr] = trc[j];
    }
}

// ---------------- fallback fp32 kernels (round-0, small ws) ---------------
#define BK 16
__global__ __launch_bounds__(256) void stdp_fwd_if(
    const float* __restrict__ x, const float* __restrict__ w,
    float* __restrict__ v, float* __restrict__ s, float* __restrict__ trace)
{
    __shared__ float as[BK][64];
    __shared__ float bs[BK][64];
    const int tid = threadIdx.x;
    const int tx = tid & 15, ty = tid >> 4;
    const int b0 = blockIdx.y * 64, h0 = blockIdx.x * 64;
    const int row = tid >> 2, kq = (tid & 3) * 4;
    float acc[4][4] = {};
    for (int k0 = 0; k0 < DIM; k0 += BK) {
        float4 ga = *(const float4*)&x[(size_t)(b0 + row) * DIM + k0 + kq];
        float4 gb = *(const float4*)&w[(size_t)(h0 + row) * DIM + k0 + kq];
        __syncthreads();
        as[kq + 0][row] = ga.x; as[kq + 1][row] = ga.y;
        as[kq + 2][row] = ga.z; as[kq + 3][row] = ga.w;
        bs[kq + 0][row] = gb.x; bs[kq + 1][row] = gb.y;
        bs[kq + 2][row] = gb.z; bs[kq + 3][row] = gb.w;
        __syncthreads();
#pragma unroll
        for (int kk = 0; kk < BK; ++kk) {
            float4 af = *(const float4*)&as[kk][ty * 4];
            float4 bf = *(const float4*)&bs[kk][tx * 4];
            float av[4] = {af.x, af.y, af.z, af.w};
            float bv[4] = {bf.x, bf.y, bf.z, bf.w};
#pragma unroll
            for (int m = 0; m < 4; ++m)
#pragma unroll
                for (int n = 0; n < 4; ++n)
                    acc[m][n] = fmaf(av[m], bv[n], acc[m][n]);
        }
    }
#pragma unroll
    for (int m = 0; m < 4; ++m) {
        size_t idx = (size_t)(b0 + ty * 4 + m) * HID + h0 + tx * 4;
        float4 vv = *(float4*)&v[idx];
        float4 tr = *(float4*)&trace[idx];
        float4 sv;
        float* vvp = &vv.x; float* trp = &tr.x; float* svp = &sv.x;
#pragma unroll
        for (int n = 0; n < 4; ++n) {
            float nv = vvp[n] + acc[m][n];
            float sp = (nv >= 1.0f) ? 1.0f : 0.0f;
            vvp[n] = (nv >= 1.0f) ? 0.0f : nv;
            svp[n] = sp; trp[n] += sp;
        }
        *(float4*)&v[idx] = vv;
        *(float4*)&s[idx] = sv;
        *(float4*)&trace[idx] = tr;
    }
}

__global__ __launch_bounds__(256) void stdp_wupd(
    const float* __restrict__ x, const float* __restrict__ s,
    float* __restrict__ w)
{
    __shared__ float ss[BK][64];
    __shared__ float xs[BK][64];
    const int tid = threadIdx.x;
    const int tx = tid & 15, ty = tid >> 4;
    const int h0 = blockIdx.y * 64, d0 = blockIdx.x * 64;
    const int krow = tid >> 4, c4 = (tid & 15) * 4;
    float acc[4][4] = {};
    for (int bk0 = 0; bk0 < BATCH; bk0 += BK) {
        float4 gs = *(const float4*)&s[(size_t)(bk0 + krow) * HID + h0 + c4];
        float4 gx = *(const float4*)&x[(size_t)(bk0 + krow) * DIM + d0 + c4];
        __syncthreads();
        *(float4*)&ss[krow][c4] = gs;
        *(float4*)&xs[krow][c4] = gx;
        __syncthreads();
#pragma unroll
        for (int kk = 0; kk < BK; ++kk) {
            float4 af = *(const float4*)&ss[kk][ty * 4];
            float4 bf = *(const float4*)&xs[kk][tx * 4];
            float av[4] = {af.x, af.y, af.z, af.w};
            float bv[4] = {bf.x, bf.y, bf.z, bf.w};
#pragma unroll
            for (int m = 0; m < 4; ++m)
#pragma unroll
                for (int n = 0; n < 4; ++n)
                    acc[m][n] = fmaf(av[m], bv[n], acc[m][n]);
        }
    }
#pragma unroll
    for (int m = 0; m < 4; ++m) {
        size_t idx = (size_t)(h0 + ty * 4 + m) * DIM + d0 + tx * 4;
        float4 wv = *(float4*)&w[idx];
        wv.x = fmaf(LR_OVER_B, acc[m][0], wv.x);
        wv.y = fmaf(LR_OVER_B, acc[m][1], wv.y);
        wv.z = fmaf(LR_OVER_B, acc[m][2], wv.z);
        wv.w = fmaf(LR_OVER_B, acc[m][3], wv.w);
        *(float4*)&w[idx] = wv;
    }
}

extern "C" void kernel_launch(void* const* d_in, const int* in_sizes, int n_in,
                              void* d_out, int out_size, void* d_ws, size_t ws_size,
                              hipStream_t stream) {
    (void)in_sizes; (void)n_in;
    const float* x_seq  = (const float*)d_in[0];   // [T, B, D]
    const float* weight = (const float*)d_in[1];   // [H, D]
    float* out = (float*)d_out;                    // [B, H]

    const size_t WN = (size_t)HID * DIM;
    const size_t BH = (size_t)BATCH * HID;
    const size_t XN = (size_t)T_STEPS * BATCH * DIM;  // 13107200

    // ws: XF (2XN us) | XW (2XN us) | sex (256*2048 us) | wex (256*16384 us)
    //     | flagS (256 u32) | flagW (256 u32)
    const size_t sex_us  = 256 * 2048;
    const size_t wex_us  = (size_t)256 * 16384;
    const size_t need = (4 * XN + sex_us + wex_us) * 2 + 512 * 4;

    if (ws_size >= need) {
        ushort* XF   = (ushort*)d_ws;
        ushort* XW   = XF + 2 * XN;
        ushort* sexp = XW + 2 * XN;
        ushort* wexp = sexp + sex_us;
        unsigned* flagS = (unsigned*)(wexp + wex_us);
        unsigned* flagW = flagS + 256;

        hipMemsetAsync(flagS, 0, 512 * 4, stream);   // reset handshake flags
        prep_fwd<<<T_STEPS * 16, 256, 0, stream>>>(x_seq, XF);
        prep_wupd<<<T_STEPS * 64, 256, 0, stream>>>(x_seq, XW);

        hipFuncSetAttribute(reinterpret_cast<const void*>(&stdp_pair),
                            hipFuncAttributeMaxDynamicSharedMemorySize,
                            SMEM_BYTES);
        stdp_pair<<<256, 512, SMEM_BYTES, stream>>>(
            XF, XW, weight, out, sexp, wexp, flagS, flagW);
    } else {
        // fallback: fp32 VALU path (needs ~12.6 MB)
        float* w = (float*)d_ws;
        float* v = w + WN;
        float* s = v + BH;
        hipMemcpyAsync(w, weight, WN * 4, hipMemcpyDeviceToDevice, stream);
        hipMemsetAsync(v, 0, BH * 4, stream);
        hipMemsetAsync(out, 0, (size_t)out_size * 4, stream);
        dim3 blkA(256), grdA(HID / 64, BATCH / 64);
        dim3 blkB(256), grdB(DIM / 64, HID / 64);
        for (int t = 0; t < T_STEPS; ++t) {
            const float* xt = x_seq + (size_t)t * BATCH * DIM;
            stdp_fwd_if<<<grdA, blkA, 0, stream>>>(xt, w, v, s, out);
            if (t < T_STEPS - 1) {
                stdp_wupd<<<grdB, blkB, 0, stream>>>(xt, s, w);
            }
        }
    }
}